// Round 4
// baseline (178.924 us; speedup 1.0000x reference)
//
#include <hip/hip_runtime.h>

// SAGPool on MI355X, round 2 design (resubmit #2 after broker timeouts):
// multi-kernel row-split pipeline.
// Graphs are contiguous 64-node blocks; A is block-diagonal 64x64.
// T' = H@W is row-local, so each graph splits into two 32-row blocks
// (grid 256 = one block per CU). Kernel boundaries are the cross-row syncs.

#define NGRAPH 128
#define EPG    1024
#define ETOT   131072
#define DIM    128
#define KSEL   32
#define SA     68

// ---- workspace layout (floats); total ~22 MB ----
#define WS_A   0                       // 128*64*64 = 524288
#define WS_T1  524288                  // 8192*128
#define WS_T2  (WS_T1 + 1048576)
#define WS_H1  (WS_T2 + 1048576)
#define WS_H2  (WS_H1 + 1048576)
#define WS_H3  (WS_H2 + 1048576)
#define WS_PRE (WS_H3 + 1048576)       // 8192
#define WS_T3  WS_T1                   // reuse T1 slot for T3

// Swizzled LDS layout for W/T tiles: oct o (8 floats) of row k stored at
// k*140 + o*8 + (o>>2)*4.  The +16B skew every 4 octs makes the 16-colgroup
// b128 read pattern hit every bank-quad exactly twice (2-way = free).
__device__ __forceinline__ int swoff(int k, int o) {
  return k * 140 + o * 8 + ((o >> 2) << 2);
}

#define FMA8(A, xs, w0, w1) do { \
  A[0] += (xs)*(w0).x; A[1] += (xs)*(w0).y; A[2] += (xs)*(w0).z; A[3] += (xs)*(w0).w; \
  A[4] += (xs)*(w1).x; A[5] += (xs)*(w1).y; A[6] += (xs)*(w1).z; A[7] += (xs)*(w1).w; } while(0)

// ---------------------------------------------------------------------------
// Kernel 1: blocks 0..127 build+normalize adjacency -> wsA;
//           blocks 128..383 compute T1 = X @ W1 (32 rows each).
// ---------------------------------------------------------------------------
__global__ void __launch_bounds__(256, 1)
k_adj_xw(const int* __restrict__ ei, const float* __restrict__ x,
         const float* __restrict__ W1, float* __restrict__ wsA,
         float* __restrict__ T1)
{
  __shared__ float smem[6464];
  const int tid = threadIdx.x;

  if (blockIdx.x < NGRAPH) {
    const int g = blockIdx.x;
    float* sA = smem;           // 64*68
    float* dv = smem + 64 * SA; // 64
    for (int i = tid; i < 64 * SA; i += 256) sA[i] = 0.f;
    __syncthreads();
    const int* srcp = ei + g * EPG;
    const int* dstp = ei + ETOT + g * EPG;
    #pragma unroll
    for (int t = 0; t < 4; ++t) {
      int e = tid + t * 256;
      int s = srcp[e] & 63;
      int d = dstp[e] & 63;
      sA[s * SA + d] = 1.0f;
      sA[d * SA + s] = 1.0f;
    }
    __syncthreads();
    if (tid < 64) sA[tid * SA + tid] += 1.0f;   // +I (self-edge -> 2, matches ref)
    __syncthreads();
    {
      int r = tid >> 2, q = tid & 3;
      float sum = 0.f;
      int jb = q * 16;
      #pragma unroll
      for (int j = 0; j < 16; ++j) sum += sA[r * SA + jb + j];
      sum += __shfl_xor(sum, 1);
      sum += __shfl_xor(sum, 2);
      if (q == 0) dv[r] = 1.0f / sqrtf(sum);
    }
    __syncthreads();
    float* outA = wsA + g * 4096;
    for (int i = tid; i < 4096; i += 256) {
      int r = i >> 6, c = i & 63;
      outA[i] = sA[r * SA + c] * dv[r] * dv[c];
    }
  } else {
    const int row0 = (blockIdx.x - NGRAPH) * 32;
    float* sX = smem;          // 32*132 = 4224
    float* sW = smem + 4224;   // 16*140 = 2240
    {
      const float4* src = (const float4*)(x + row0 * DIM);
      for (int i = tid; i < 1024; i += 256) {
        int r = i >> 5, q = i & 31;
        *(float4*)&sX[r * 132 + q * 4] = src[i];
      }
    }
    const int rg = tid >> 4, cg = tid & 15;
    const int r0 = rg * 2, c0 = cg * 8;
    float acc[2][8];
    #pragma unroll
    for (int rr = 0; rr < 2; ++rr)
      #pragma unroll
      for (int cc = 0; cc < 8; ++cc) acc[rr][cc] = 0.f;

    for (int kc = 0; kc < 8; ++kc) {
      __syncthreads();
      const float4* wsrc = (const float4*)(W1 + kc * 16 * DIM);
      for (int i = tid; i < 512; i += 256) {
        int k = i >> 5, q = i & 31;
        *(float4*)&sW[swoff(k, q >> 1) + (q & 1) * 4] = wsrc[i];
      }
      __syncthreads();
      #pragma unroll
      for (int kq = 0; kq < 4; ++kq) {
        const int kk = kq * 4, kg = kc * 16 + kk;
        float4 x0 = *(const float4*)&sX[r0 * 132 + kg];
        float4 x1 = *(const float4*)&sX[(r0 + 1) * 132 + kg];
        float4 w0[4], w1[4];
        #pragma unroll
        for (int j = 0; j < 4; ++j) {
          int base = swoff(kk + j, cg);
          w0[j] = *(const float4*)&sW[base];
          w1[j] = *(const float4*)&sW[base + 4];
        }
        FMA8(acc[0], x0.x, w0[0], w1[0]); FMA8(acc[0], x0.y, w0[1], w1[1]);
        FMA8(acc[0], x0.z, w0[2], w1[2]); FMA8(acc[0], x0.w, w0[3], w1[3]);
        FMA8(acc[1], x1.x, w0[0], w1[0]); FMA8(acc[1], x1.y, w0[1], w1[1]);
        FMA8(acc[1], x1.z, w0[2], w1[2]); FMA8(acc[1], x1.w, w0[3], w1[3]);
      }
    }
    #pragma unroll
    for (int rr = 0; rr < 2; ++rr) {
      float4 t0 = make_float4(acc[rr][0], acc[rr][1], acc[rr][2], acc[rr][3]);
      float4 t1 = make_float4(acc[rr][4], acc[rr][5], acc[rr][6], acc[rr][7]);
      *(float4*)&T1[(row0 + r0 + rr) * DIM + c0]     = t0;
      *(float4*)&T1[(row0 + r0 + rr) * DIM + c0 + 4] = t1;
    }
  }
}

// ---------------------------------------------------------------------------
// Kernel 2 (x3): block = (graph, row-half).  h = relu(A[rows]@T + b);
// pre[row] (+)= h[row,:].wa ; optionally T' = h @ Wn.
// ---------------------------------------------------------------------------
#define FOFF_A 8960             // sT = 64*140
#define FOFF_H 11136            // sAl = 32*68
#define FOFF_W 15360            // sh = 32*132
#define FUSED_LDS_FLOATS 17600  // + sW 16*140
#define FUSED_LDS_BYTES (FUSED_LDS_FLOATS * 4)

__global__ void __launch_bounds__(256, 1)
k_fused(const float* __restrict__ Tin, const float* __restrict__ wsA,
        const float* __restrict__ bg, const float* __restrict__ waCol,
        const float* __restrict__ Wn, float* __restrict__ Hout,
        float* __restrict__ Tout, float* __restrict__ pre,
        const int first, const int do_xw)
{
  extern __shared__ float lds[];
  float* sT  = lds;            // swizzled [64][140]
  float* sAl = lds + FOFF_A;   // [32][68]
  float* sh  = lds + FOFF_H;   // [32][132]
  float* sW  = lds + FOFF_W;   // swizzled [16][140]
  const int tid = threadIdx.x;
  const int g = blockIdx.x >> 1;
  const int rbase = (blockIdx.x & 1) * 32;
  const int growbase = g * 64 + rbase;

  { // stage T_g (swizzled) + A rows
    const float4* src = (const float4*)(Tin + g * 64 * DIM);
    for (int i = tid; i < 2048; i += 256) {
      int k = i >> 5, q = i & 31;
      *(float4*)&sT[swoff(k, q >> 1) + (q & 1) * 4] = src[i];
    }
    const float* asrc = wsA + g * 4096 + rbase * 64;
    for (int i = tid; i < 2048; i += 256)
      sAl[(i >> 6) * SA + (i & 63)] = asrc[i];
  }
  __syncthreads();

  const int rg = tid >> 4, cg = tid & 15;
  const int r0 = rg * 2, c0 = cg * 8;

  // ---- phase A: h = relu(A@T + b) ----
  float4 bv0 = *(const float4*)&bg[c0];
  float4 bv1 = *(const float4*)&bg[c0 + 4];
  float acc[2][8];
  #pragma unroll
  for (int rr = 0; rr < 2; ++rr) {
    acc[rr][0] = bv0.x; acc[rr][1] = bv0.y; acc[rr][2] = bv0.z; acc[rr][3] = bv0.w;
    acc[rr][4] = bv1.x; acc[rr][5] = bv1.y; acc[rr][6] = bv1.z; acc[rr][7] = bv1.w;
  }
  #pragma unroll
  for (int kq = 0; kq < 16; ++kq) {
    const int kk = kq * 4;
    float4 a0 = *(const float4*)&sAl[r0 * SA + kk];
    float4 a1 = *(const float4*)&sAl[(r0 + 1) * SA + kk];
    float4 t0[4], t1[4];
    #pragma unroll
    for (int j = 0; j < 4; ++j) {
      int base = swoff(kk + j, cg);
      t0[j] = *(const float4*)&sT[base];
      t1[j] = *(const float4*)&sT[base + 4];
    }
    FMA8(acc[0], a0.x, t0[0], t1[0]); FMA8(acc[0], a0.y, t0[1], t1[1]);
    FMA8(acc[0], a0.z, t0[2], t1[2]); FMA8(acc[0], a0.w, t0[3], t1[3]);
    FMA8(acc[1], a1.x, t0[0], t1[0]); FMA8(acc[1], a1.y, t0[1], t1[1]);
    FMA8(acc[1], a1.z, t0[2], t1[2]); FMA8(acc[1], a1.w, t0[3], t1[3]);
  }
  float4 wa0 = *(const float4*)&waCol[c0];
  float4 wa1 = *(const float4*)&waCol[c0 + 4];
  float pp[2];
  #pragma unroll
  for (int rr = 0; rr < 2; ++rr) {
    float4 o0, o1;
    o0.x = fmaxf(acc[rr][0], 0.f); o0.y = fmaxf(acc[rr][1], 0.f);
    o0.z = fmaxf(acc[rr][2], 0.f); o0.w = fmaxf(acc[rr][3], 0.f);
    o1.x = fmaxf(acc[rr][4], 0.f); o1.y = fmaxf(acc[rr][5], 0.f);
    o1.z = fmaxf(acc[rr][6], 0.f); o1.w = fmaxf(acc[rr][7], 0.f);
    *(float4*)&sh[(r0 + rr) * 132 + c0]     = o0;
    *(float4*)&sh[(r0 + rr) * 132 + c0 + 4] = o1;
    *(float4*)&Hout[(growbase + r0 + rr) * DIM + c0]     = o0;
    *(float4*)&Hout[(growbase + r0 + rr) * DIM + c0 + 4] = o1;
    pp[rr] = o0.x*wa0.x + o0.y*wa0.y + o0.z*wa0.z + o0.w*wa0.w
           + o1.x*wa1.x + o1.y*wa1.y + o1.z*wa1.z + o1.w*wa1.w;
  }
  #pragma unroll
  for (int rr = 0; rr < 2; ++rr) {
    pp[rr] += __shfl_xor(pp[rr], 1);
    pp[rr] += __shfl_xor(pp[rr], 2);
    pp[rr] += __shfl_xor(pp[rr], 4);
    pp[rr] += __shfl_xor(pp[rr], 8);
  }
  if (cg == 0) {
    #pragma unroll
    for (int rr = 0; rr < 2; ++rr) {
      int row = growbase + r0 + rr;
      if (first) pre[row] = pp[rr];
      else       pre[row] += pp[rr];
    }
  }

  // ---- phase B: T' = h @ Wn ----
  if (do_xw) {
    float acc2[2][8];
    #pragma unroll
    for (int rr = 0; rr < 2; ++rr)
      #pragma unroll
      for (int cc = 0; cc < 8; ++cc) acc2[rr][cc] = 0.f;
    for (int kc = 0; kc < 8; ++kc) {
      __syncthreads();
      const float4* wsrc = (const float4*)(Wn + kc * 16 * DIM);
      for (int i = tid; i < 512; i += 256) {
        int k = i >> 5, q = i & 31;
        *(float4*)&sW[swoff(k, q >> 1) + (q & 1) * 4] = wsrc[i];
      }
      __syncthreads();
      #pragma unroll
      for (int kq = 0; kq < 4; ++kq) {
        const int kk = kq * 4, kg = kc * 16 + kk;
        float4 h0 = *(const float4*)&sh[r0 * 132 + kg];
        float4 h1 = *(const float4*)&sh[(r0 + 1) * 132 + kg];
        float4 w0[4], w1[4];
        #pragma unroll
        for (int j = 0; j < 4; ++j) {
          int base = swoff(kk + j, cg);
          w0[j] = *(const float4*)&sW[base];
          w1[j] = *(const float4*)&sW[base + 4];
        }
        FMA8(acc2[0], h0.x, w0[0], w1[0]); FMA8(acc2[0], h0.y, w0[1], w1[1]);
        FMA8(acc2[0], h0.z, w0[2], w1[2]); FMA8(acc2[0], h0.w, w0[3], w1[3]);
        FMA8(acc2[1], h1.x, w0[0], w1[0]); FMA8(acc2[1], h1.y, w0[1], w1[1]);
        FMA8(acc2[1], h1.z, w0[2], w1[2]); FMA8(acc2[1], h1.w, w0[3], w1[3]);
      }
    }
    #pragma unroll
    for (int rr = 0; rr < 2; ++rr) {
      float4 t0 = make_float4(acc2[rr][0], acc2[rr][1], acc2[rr][2], acc2[rr][3]);
      float4 t1 = make_float4(acc2[rr][4], acc2[rr][5], acc2[rr][6], acc2[rr][7]);
      *(float4*)&Tout[(growbase + r0 + rr) * DIM + c0]     = t0;
      *(float4*)&Tout[(growbase + r0 + rr) * DIM + c0 + 4] = t1;
    }
  }
}

// ---------------------------------------------------------------------------
// Kernel 3: per-graph score = tanh(A@pre + ba), top-K, readout, MLP -> out
// ---------------------------------------------------------------------------
__global__ void __launch_bounds__(256, 1)
k_final(const float* __restrict__ wsA, const float* __restrict__ pre,
        const float* __restrict__ h1g, const float* __restrict__ h2g,
        const float* __restrict__ h3g, const float* __restrict__ ba,
        const float* __restrict__ M1, const float* __restrict__ c1,
        const float* __restrict__ M2, const float* __restrict__ c2,
        const float* __restrict__ M3, const float* __restrict__ c3,
        float* __restrict__ out)
{
  __shared__ float spre[64], ssc[64], ssel[64];
  __shared__ float ro[768], mh[256], hm[128], h2m[64];
  const int g = blockIdx.x, tid = threadIdx.x;

  if (tid < 64) spre[tid] = pre[g * 64 + tid];
  __syncthreads();
  { // score = tanh(A@pre + ba)
    int r = tid >> 2, q = tid & 3;
    const float* Ar = wsA + g * 4096 + r * 64;
    float partial = 0.f;
    int jb = q * 16;
    #pragma unroll
    for (int j = 0; j < 16; ++j) partial += Ar[jb + j] * spre[jb + j];
    partial += __shfl_xor(partial, 1);
    partial += __shfl_xor(partial, 2);
    if (q == 0) ssc[r] = tanhf(partial + ba[0]);
  }
  __syncthreads();
  if (tid < 64) { // top-K by rank (value desc, index asc = lax.top_k ties)
    float mys = ssc[tid];
    int cnt = 0;
    for (int j = 0; j < 64; ++j) {
      float sj = ssc[j];
      cnt += (sj > mys || (sj == mys && j < tid)) ? 1 : 0;
    }
    ssel[tid] = (cnt < KSEL) ? 1.0f : 0.0f;
  }
  __syncthreads();
  // readout: mean || max over selected, score-scaled rows
  for (int c = tid; c < 384; c += 256) {
    int which = c >> 7, cc = c & 127;
    const float* hb = ((which == 0) ? h1g : (which == 1) ? h2g : h3g) + g * 64 * DIM;
    float sum = 0.f, mx = -1e30f;
    for (int i = 0; i < 64; ++i) {
      if (ssel[i] > 0.5f) {
        float v = ssc[i] * hb[i * DIM + cc];
        sum += v;
        mx = fmaxf(mx, v);
      }
    }
    ro[c]       = sum * (1.0f / KSEL);
    ro[384 + c] = mx;
  }
  __syncthreads();
  // MLP: 768 -> 128 -> 64 -> 10
  {
    int j = tid & 127, half = tid >> 7;
    float acc = 0.f;
    int k0 = half * 384;
    for (int k = k0; k < k0 + 384; k += 4) {
      float4 r4 = *(const float4*)&ro[k];
      acc += r4.x * M1[(k + 0) * DIM + j];
      acc += r4.y * M1[(k + 1) * DIM + j];
      acc += r4.z * M1[(k + 2) * DIM + j];
      acc += r4.w * M1[(k + 3) * DIM + j];
    }
    mh[half * 128 + j] = acc;
  }
  __syncthreads();
  if (tid < 128) hm[tid] = fmaxf(mh[tid] + mh[128 + tid] + c1[tid], 0.f);
  __syncthreads();
  if (tid < 64) {
    float acc = c2[tid];
    for (int k = 0; k < 128; ++k) acc += hm[k] * M2[k * 64 + tid];
    h2m[tid] = fmaxf(acc, 0.f);
  }
  __syncthreads();
  if (tid < 10) {
    float acc = c3[tid];
    for (int k = 0; k < 64; ++k) acc += h2m[k] * M3[k * 10 + tid];
    out[g * 10 + tid] = acc;
  }
}

extern "C" void kernel_launch(void* const* d_in, const int* in_sizes, int n_in,
                              void* d_out, int out_size, void* d_ws, size_t ws_size,
                              hipStream_t stream) {
  const float* x  = (const float*)d_in[0];
  const int*   ei = (const int*)d_in[1];
  const float* W1 = (const float*)d_in[3];
  const float* b1 = (const float*)d_in[4];
  const float* W2 = (const float*)d_in[5];
  const float* b2 = (const float*)d_in[6];
  const float* W3 = (const float*)d_in[7];
  const float* b3 = (const float*)d_in[8];
  const float* Wa = (const float*)d_in[9];
  const float* ba = (const float*)d_in[10];
  const float* M1 = (const float*)d_in[11];
  const float* c1 = (const float*)d_in[12];
  const float* M2 = (const float*)d_in[13];
  const float* c2 = (const float*)d_in[14];
  const float* M3 = (const float*)d_in[15];
  const float* c3 = (const float*)d_in[16];
  float* out = (float*)d_out;

  float* ws  = (float*)d_ws;
  float* wsA = ws + WS_A;
  float* T1  = ws + WS_T1;
  float* T2  = ws + WS_T2;
  float* T3  = ws + WS_T3;
  float* H1  = ws + WS_H1;
  float* H2  = ws + WS_H2;
  float* H3  = ws + WS_H3;
  float* pre = ws + WS_PRE;

  (void)hipFuncSetAttribute(reinterpret_cast<const void*>(k_fused),
                            hipFuncAttributeMaxDynamicSharedMemorySize, FUSED_LDS_BYTES);

  k_adj_xw<<<NGRAPH + 256, 256, 0, stream>>>(ei, x, W1, wsA, T1);
  k_fused<<<256, 256, FUSED_LDS_BYTES, stream>>>(T1, wsA, b1, Wa,           W2, H1, T2, pre, 1, 1);
  k_fused<<<256, 256, FUSED_LDS_BYTES, stream>>>(T2, wsA, b2, Wa + DIM,     W3, H2, T3, pre, 0, 1);
  k_fused<<<256, 256, FUSED_LDS_BYTES, stream>>>(T3, wsA, b3, Wa + 2 * DIM, W3, H3, T2, pre, 0, 0);
  k_final<<<NGRAPH, 256, 0, stream>>>(wsA, pre, H1, H2, H3, ba,
                                      M1, c1, M2, c2, M3, c3, out);
}